// Round 11
// baseline (306.166 us; speedup 1.0000x reference)
//
#include <hip/hip_runtime.h>
#include <hip/hip_bf16.h>
#include <stdint.h>

typedef _Float16 f16;
typedef _Float16 f16x8 __attribute__((ext_vector_type(8)));
typedef float f32x4 __attribute__((ext_vector_type(4)));

#define AS1 __attribute__((address_space(1)))
#define AS3 __attribute__((address_space(3)))

// ---------------------------------------------------------------------------
// Merged transpose + fp32->fp16 convert for all three inputs, one launch.
// Flat grid decode: [0,8192) x-batches, [8192,9216) Wqkv, [9216,9472) Wout.
// Block 0 additionally zeros the 128 split-K counters (runs before syk).
// ---------------------------------------------------------------------------
__global__ __launch_bounds__(256) void tr_cvt_all(
    const float* __restrict__ x, const float* __restrict__ Wqkv,
    const float* __restrict__ Wout,
    f16* __restrict__ xT, f16* __restrict__ WqkvT, f16* __restrict__ WoutT,
    unsigned* __restrict__ cnt)
{
    __shared__ float tile[64][65];
    const int id = blockIdx.x;
    const int t = threadIdx.x;
    if (id == 0 && t < 128) cnt[t] = 0u;

    const float* src; f16* dst; int R, C, c0, r0;
    if (id < 8192) {
        const int b = id >> 10, rem = id & 1023;
        src = x + (size_t)b * 4096 * 1024;
        dst = xT + (size_t)b * 4096 * 1024;
        R = 4096; C = 1024;
        c0 = (rem & 15) * 64; r0 = (rem >> 4) * 64;
    } else if (id < 9216) {
        const int rem = id - 8192;
        src = Wqkv; dst = WqkvT;
        R = 1024; C = 4096;
        c0 = (rem & 63) * 64; r0 = (rem >> 6) * 64;
    } else {
        const int rem = id - 9216;
        src = Wout; dst = WoutT;
        R = 1024; C = 1024;
        c0 = (rem & 15) * 64; r0 = (rem >> 4) * 64;
    }

    {
        const int cc = (t & 15) * 4;
        const int rr = t >> 4;
#pragma unroll
        for (int p = 0; p < 4; ++p) {
            const int r = rr + p * 16;
            const float4 v = *(const float4*)(src + (size_t)(r0 + r) * C + c0 + cc);
            tile[r][cc + 0] = v.x; tile[r][cc + 1] = v.y;
            tile[r][cc + 2] = v.z; tile[r][cc + 3] = v.w;
        }
    }
    __syncthreads();
    {
        const int rq = (t & 15) * 4;
        const int cp = t >> 4;
#pragma unroll
        for (int p = 0; p < 4; ++p) {
            const int c = cp + p * 16;
            ushort4 o;
            f16 h0 = (f16)tile[rq + 0][c];
            f16 h1 = (f16)tile[rq + 1][c];
            f16 h2 = (f16)tile[rq + 2][c];
            f16 h3 = (f16)tile[rq + 3][c];
            o.x = __builtin_bit_cast(unsigned short, h0);
            o.y = __builtin_bit_cast(unsigned short, h1);
            o.z = __builtin_bit_cast(unsigned short, h2);
            o.w = __builtin_bit_cast(unsigned short, h3);
            *(ushort4*)(dst + (size_t)(c0 + c) * R + r0 + rq) = o;
        }
    }
}

// ---------------------------------------------------------------------------
// r5-exact 256x256-tile, BK=64, 512-thread (8-wave, 2x4) GEMM core.
// Double-buffered LDS, global_load_lds-16B staging one step ahead, counted
// s_waitcnt vmcnt(8) (never 0 mid-loop), raw barriers, chunk-XOR swizzle.
// Measured: 74.8us / MfmaUtil 39.4% / 0 bank conflicts (round 5).
// ---------------------------------------------------------------------------
__device__ __forceinline__ void stage256(
    const f16* __restrict__ src, int ld, char* ldsbase, int tid)
{
    const int lane = tid & 63;
    const int gch = ((lane & 7) ^ (lane >> 3)) * 8;   // inverse-swizzled source
    const int rowl = tid >> 3;
    const int wbase = (tid >> 3) & ~7;                // wave-uniform
#pragma unroll
    for (int p = 0; p < 4; ++p) {
        const f16* s = src + (size_t)(p * 64 + rowl) * ld + gch;
        __builtin_amdgcn_global_load_lds(
            (const AS1 uint32_t*)s,
            (AS3 uint32_t*)(ldsbase + (p * 64 + wbase) * 128), 16, 0, 0);
    }
}

__device__ __forceinline__ void gemm256_core(
    const f16* __restrict__ A, const f16* __restrict__ Bt,
    int lda, int ldb, int nsteps,
    f16* As, f16* Bs, f32x4 (&acc)[8][4], int tid)
{
    const int lane = tid & 63, w = tid >> 6;
    const int wr = w >> 2, wc = w & 3;
    const int cl = lane & 15, kg = lane >> 4, b7 = lane & 7;

    stage256(A, lda, (char*)As, tid);
    stage256(Bt, ldb, (char*)Bs, tid);

#pragma unroll 1
    for (int t = 0; t < nsteps; ++t) {
        const int cur = t & 1;
        if (t + 1 < nsteps) {
            const int k0 = (t + 1) * 64;
            stage256(A + k0, lda, (char*)As + (cur ^ 1) * 32768, tid);
            stage256(Bt + k0, ldb, (char*)Bs + (cur ^ 1) * 32768, tid);
            asm volatile("s_waitcnt vmcnt(8)" ::: "memory");
        } else {
            asm volatile("s_waitcnt vmcnt(0)" ::: "memory");
        }
        __builtin_amdgcn_s_barrier();
        const f16* Ab = As + cur * 16384;
        const f16* Bb = Bs + cur * 16384;
#pragma unroll
        for (int kk = 0; kk < 2; ++kk) {
            const int ch = (kk * 4 + kg) ^ b7;
            f16x8 af[8], bf[4];
#pragma unroll
            for (int i = 0; i < 8; ++i)
                af[i] = *(const f16x8*)&Ab[(wr * 128 + i * 16 + cl) * 64 + ch * 8];
#pragma unroll
            for (int j = 0; j < 4; ++j)
                bf[j] = *(const f16x8*)&Bb[(wc * 64 + j * 16 + cl) * 64 + ch * 8];
#pragma unroll
            for (int i = 0; i < 8; ++i)
#pragma unroll
                for (int j = 0; j < 4; ++j)
                    acc[i][j] = __builtin_amdgcn_mfma_f32_16x16x32_f16(af[i], bf[j], acc[i][j], 0, 0, 0);
        }
        __builtin_amdgcn_s_barrier();
    }
}

// ---------------------------------------------------------------------------
// K1 with fused split-K reduction (last-block pattern):
// each block writes its f16 partial to Gp[s][b][tile]; threadfence; atomicAdd
// on cnt[b*16+tile]; second arrival (odd old value) re-reads partner partial,
// adds to its own f16-rounded acc (order-independent => deterministic), and
// writes the final G tile. Counters are zeroed each call by tr_cvt_all.
// grid: 256 blocks (16 tiles x 8 batch x 2 splits), XCD-chunked swizzle.
// ---------------------------------------------------------------------------
__global__ __launch_bounds__(512, 2) void gemm_syk256(
    const f16* __restrict__ xT, f16* __restrict__ Gp,
    f16* __restrict__ G, unsigned* __restrict__ cnt)
{
    __shared__ f16 As[2 * 256 * 64];
    __shared__ f16 Bs[2 * 256 * 64];
    __shared__ unsigned sold;
    const int orig = blockIdx.x;
    const int l = (orig & 7) * 32 + (orig >> 3);   // 256 = 8*32, bijective
    const int tile = l & 15, b = (l >> 4) & 7, s = l >> 7;
    const int ti = tile >> 2, tj = tile & 3;

    const f16* base = xT + (size_t)b * (1024 * 4096) + (size_t)s * 2048;
    const f16* A  = base + (size_t)ti * 256 * 4096;
    const f16* Bt = base + (size_t)tj * 256 * 4096;

    f32x4 acc[8][4];
#pragma unroll
    for (int i = 0; i < 8; ++i)
#pragma unroll
        for (int j = 0; j < 4; ++j) acc[i][j] = f32x4{0.f, 0.f, 0.f, 0.f};

    gemm256_core(A, Bt, 4096, 4096, 32, As, Bs, acc, threadIdx.x);

    const int tid = threadIdx.x;
    const int lane = tid & 63, w = tid >> 6;
    const int wr = w >> 2, wc = w & 3;
    const int cl = lane & 15, rg = lane >> 4;

    // 1) write own partial (f16) to Gp[s][b][tile], local 256x256 coords
    f16* myGp = Gp + ((((size_t)s * 8 + b) * 16) + tile) * 65536;
#pragma unroll
    for (int i = 0; i < 8; ++i)
#pragma unroll
        for (int j = 0; j < 4; ++j)
#pragma unroll
            for (int q = 0; q < 4; ++q) {
                const int lr = wr * 128 + i * 16 + rg * 4 + q;
                const int lc = wc * 64 + j * 16 + cl;
                myGp[lr * 256 + lc] = (f16)acc[i][j][q];
            }

    // 2) signal; second arrival merges
    __threadfence();
    __syncthreads();
    if (tid == 0) sold = atomicAdd(&cnt[b * 16 + tile], 1u);
    __syncthreads();
    if ((sold & 1u) == 0u) return;   // first arrival done

    __threadfence();                  // acquire partner's writes
    const f16* other = Gp + ((((size_t)(s ^ 1) * 8 + b) * 16) + tile) * 65536;
    f16* Gt = G + (size_t)b * 1048576 + (size_t)(ti * 256) * 1024 + tj * 256;
#pragma unroll
    for (int i = 0; i < 8; ++i)
#pragma unroll
        for (int j = 0; j < 4; ++j)
#pragma unroll
            for (int q = 0; q < 4; ++q) {
                const int lr = wr * 128 + i * 16 + rg * 4 + q;
                const int lc = wc * 64 + j * 16 + cl;
                const float mine = (float)(f16)acc[i][j][q];   // rounded: order-invariant
                const float sum = mine + (float)other[lr * 256 + lc];
                Gt[(size_t)lr * 1024 + lc] = (f16)sum;
            }
}

// ---------------------------------------------------------------------------
// K2 fused (256^2): UW2[b] = [Wq^T G_b ; Wv^T G_b], K=1024.
// grid: 256 blocks (4 N x 8 M x 8 batch), XCD-chunked swizzle.
// ---------------------------------------------------------------------------
__global__ __launch_bounds__(512, 2) void gemm_qv256(
    const f16* __restrict__ WqkvT, const f16* __restrict__ G,
    f16* __restrict__ UW2)
{
    __shared__ f16 As[2 * 256 * 64];
    __shared__ f16 Bs[2 * 256 * 64];
    const int orig = blockIdx.x;
    const int l = (orig & 7) * 32 + (orig >> 3);
    const int bx = l & 3, by = (l >> 2) & 7, b = l >> 5;
    const int arow = (by < 4) ? by * 256 : 2048 + (by - 4) * 256;  // skip Wk

    const f16* A  = WqkvT + (size_t)arow * 1024;
    const f16* Bt = G + (size_t)b * 1048576 + (size_t)bx * 256 * 1024;

    f32x4 acc[8][4];
#pragma unroll
    for (int i = 0; i < 8; ++i)
#pragma unroll
        for (int j = 0; j < 4; ++j) acc[i][j] = f32x4{0.f, 0.f, 0.f, 0.f};

    gemm256_core(A, Bt, 1024, 1024, 16, As, Bs, acc, threadIdx.x);

    f16* C = UW2 + (size_t)b * 2097152;
    const int lane = threadIdx.x & 63, w = threadIdx.x >> 6;
    const int wr = w >> 2, wc = w & 3;
    const int cl = lane & 15, rg = lane >> 4;
#pragma unroll
    for (int i = 0; i < 8; ++i)
#pragma unroll
        for (int j = 0; j < 4; ++j) {
            const int cc = bx * 256 + wc * 64 + j * 16 + cl;
#pragma unroll
            for (int q = 0; q < 4; ++q) {
                const int rr = by * 256 + wr * 128 + i * 16 + rg * 4 + q;
                C[(size_t)rr * 1024 + cc] = (f16)acc[i][j][q];
            }
        }
}

// ---------------------------------------------------------------------------
// Legacy 128x128 body (used by gemm_out only)
// ---------------------------------------------------------------------------
__device__ __forceinline__ void gemm_body(
    const f16* __restrict__ A, const f16* __restrict__ Bt,
    int lda, int ldb, int K, f16* As, f16* Bs,
    f32x4 (&acc)[4][4], int tid)
{
    const int lane = tid & 63, w = tid >> 6;
    const int wr = w >> 1, wc = w & 1;
    const int lrow = lane >> 3;
    const int lcol = (lane & 7) * 8;
    for (int k0 = 0; k0 < K; k0 += 64) {
#pragma unroll
        for (int p = 0; p < 4; ++p) {
            const f16* sa = A + (size_t)(p * 32 + w * 8 + lrow) * lda + k0 + lcol;
            __builtin_amdgcn_global_load_lds(
                (const AS1 uint32_t*)sa,
                (AS3 uint32_t*)((char*)As + p * 4096 + w * 1024), 16, 0, 0);
            const f16* sb = Bt + (size_t)(p * 32 + w * 8 + lrow) * ldb + k0 + lcol;
            __builtin_amdgcn_global_load_lds(
                (const AS1 uint32_t*)sb,
                (AS3 uint32_t*)((char*)Bs + p * 4096 + w * 1024), 16, 0, 0);
        }
        __syncthreads();
#pragma unroll
        for (int kk = 0; kk < 2; ++kk) {
            f16x8 af[4], bfr[4];
#pragma unroll
            for (int i = 0; i < 4; ++i)
                af[i] = *(const f16x8*)&As[(wr * 64 + i * 16 + (lane & 15)) * 64 + kk * 32 + (lane >> 4) * 8];
#pragma unroll
            for (int j = 0; j < 4; ++j)
                bfr[j] = *(const f16x8*)&Bs[(wc * 64 + j * 16 + (lane & 15)) * 64 + kk * 32 + (lane >> 4) * 8];
#pragma unroll
            for (int i = 0; i < 4; ++i)
#pragma unroll
                for (int j = 0; j < 4; ++j)
                    acc[i][j] = __builtin_amdgcn_mfma_f32_16x16x32_f16(af[i], bfr[j], acc[i][j], 0, 0, 0);
        }
        __syncthreads();
    }
}

// ---------------------------------------------------------------------------
// K4: d_out = O @ WoutT^T + bias.  grid (8,4), block 256. K=1024.
// ---------------------------------------------------------------------------
__global__ __launch_bounds__(256) void gemm_out(
    const f16* __restrict__ A, const f16* __restrict__ Bt,
    const float* __restrict__ bias, float* __restrict__ Cout)
{
    __shared__ f16 As[128 * 64];
    __shared__ f16 Bs[128 * 64];
    const int tn0 = blockIdx.x * 128;
    const int tm0 = blockIdx.y * 128;
    f32x4 acc[4][4];
#pragma unroll
    for (int i = 0; i < 4; ++i)
#pragma unroll
        for (int j = 0; j < 4; ++j) acc[i][j] = f32x4{0.f, 0.f, 0.f, 0.f};

    gemm_body(A + (size_t)tm0 * 1024, Bt + (size_t)tn0 * 1024,
              1024, 1024, 1024, As, Bs, acc, threadIdx.x);

    const int lane = threadIdx.x & 63, w = threadIdx.x >> 6;
    const int wr = w >> 1, wc = w & 1;
    const int cl = lane & 15, rg = lane >> 4;
#pragma unroll
    for (int i = 0; i < 4; ++i)
#pragma unroll
        for (int j = 0; j < 4; ++j) {
            const int cc = tn0 + wc * 64 + j * 16 + cl;
            const float bv = bias[cc];
#pragma unroll
            for (int q = 0; q < 4; ++q) {
                const int rr = tm0 + wr * 64 + i * 16 + rg * 4 + q;
                Cout[(size_t)rr * 1024 + cc] = acc[i][j][q] + bv;
            }
        }
}

// ---------------------------------------------------------------------------
// Per (b,h): dots = U_h * Wk_h^T, vv = W2_h * Wv2_h^T  (64x64, K=1024),
// softmax(dots*0.125), out = attn @ vv -> O (f16)
// grid: (16 heads, 8 batches), block 512 (8 waves)
// ---------------------------------------------------------------------------
__global__ __launch_bounds__(512) void attn_small(
    const f16* __restrict__ UW2, const f16* __restrict__ WqkvT,
    f16* __restrict__ O)
{
    __shared__ float dots[64][66];
    __shared__ float vv[64][66];
    const int h = blockIdx.x, b = blockIdx.y;
    const int tid = threadIdx.x, lane = tid & 63, w = tid >> 6;
    const int isVV = w >> 2;
    const int kq = w & 3;

    const f16* Arows = UW2 + (size_t)b * (2048 * 1024)
                           + (size_t)isVV * (1024 * 1024) + (size_t)h * 64 * 1024;
    const f16* Brows = WqkvT + (size_t)(isVV ? 3072 : 1024) * 1024 + (size_t)h * 64 * 1024;

    f32x4 acc[4][4];
#pragma unroll
    for (int i = 0; i < 4; ++i)
#pragma unroll
        for (int j = 0; j < 4; ++j) acc[i][j] = f32x4{0.f, 0.f, 0.f, 0.f};

    const int cl = lane & 15, kg = lane >> 4;
    for (int ks = 0; ks < 8; ++ks) {
        const int k0 = kq * 256 + ks * 32 + kg * 8;
        f16x8 af[4], bfr[4];
#pragma unroll
        for (int i = 0; i < 4; ++i)
            af[i] = *(const f16x8*)(Arows + (size_t)(i * 16 + cl) * 1024 + k0);
#pragma unroll
        for (int j = 0; j < 4; ++j)
            bfr[j] = *(const f16x8*)(Brows + (size_t)(j * 16 + cl) * 1024 + k0);
#pragma unroll
        for (int i = 0; i < 4; ++i)
#pragma unroll
            for (int j = 0; j < 4; ++j)
                acc[i][j] = __builtin_amdgcn_mfma_f32_16x16x32_f16(af[i], bfr[j], acc[i][j], 0, 0, 0);
    }

    float (*dst)[66] = isVV ? vv : dots;
#pragma unroll
    for (int r = 0; r < 4; ++r) {
        if (kq == r) {
            if (r == 0) {
#pragma unroll
                for (int i = 0; i < 4; ++i)
#pragma unroll
                    for (int j = 0; j < 4; ++j)
#pragma unroll
                        for (int q = 0; q < 4; ++q)
                            dst[i * 16 + kg * 4 + q][j * 16 + cl] = acc[i][j][q];
            } else {
#pragma unroll
                for (int i = 0; i < 4; ++i)
#pragma unroll
                    for (int j = 0; j < 4; ++j)
#pragma unroll
                        for (int q = 0; q < 4; ++q)
                            dst[i * 16 + kg * 4 + q][j * 16 + cl] += acc[i][j][q];
            }
        }
        __syncthreads();
    }

    if (tid < 64) {
        const int r = tid;
        float mx = -1e30f;
        for (int e = 0; e < 64; ++e) {
            const float v = dots[r][e] * 0.125f;
            dots[r][e] = v;
            mx = fmaxf(mx, v);
        }
        float s = 0.f;
        for (int e = 0; e < 64; ++e) {
            const float v = __expf(dots[r][e] - mx);
            dots[r][e] = v;
            s += v;
        }
        const float inv = 1.f / s;
        for (int e = 0; e < 64; ++e) dots[r][e] *= inv;
    }
    __syncthreads();

    {
        const int r = tid >> 3, f0 = (tid & 7) * 8;
        float o[8];
#pragma unroll
        for (int i = 0; i < 8; ++i) o[i] = 0.f;
        for (int e = 0; e < 64; ++e) {
            const float a = dots[r][e];
#pragma unroll
            for (int i = 0; i < 8; ++i) o[i] += a * vv[e][f0 + i];
        }
        f16* Od = O + (size_t)b * 64 * 1024 + (size_t)r * 1024 + h * 64 + f0;
#pragma unroll
        for (int i = 0; i < 8; ++i) Od[i] = (f16)o[i];
    }
}

// ---------------------------------------------------------------------------
extern "C" void kernel_launch(void* const* d_in, const int* in_sizes, int n_in,
                              void* d_out, int out_size, void* d_ws, size_t ws_size,
                              hipStream_t stream)
{
    const float* x    = (const float*)d_in[0];  // [8][4096][1024]
    const float* Wqkv = (const float*)d_in[1];  // [1024][4096]
    const float* Wout = (const float*)d_in[2];  // [1024][1024]
    const float* bout = (const float*)d_in[3];  // [1024]

    char* ws = (char*)d_ws;
    f16* xT       = (f16*)(ws + 0);           // [8][1024][4096]   67108864 B
    f16* WqkvT    = (f16*)(ws + 67108864);    // [4096][1024]       8388608 B
    f16* WoutT    = (f16*)(ws + 75497472);    // [1024][1024]       2097152 B
    f16* G        = (f16*)(ws + 77594624);    // [8][1024][1024]   16777216 B
    f16* Gp       = (f16*)(ws + 94371840);    // [2][8][16][65536] 33554432 B
    f16* UW2      = (f16*)(ws + 94371840);    // union w/ Gp (qv after syk)
    f16* O        = (f16*)(ws + 127926272);   // [8][64][1024]      1048576 B
    unsigned* cnt = (unsigned*)(ws + 128974848); // 128 counters       512 B

    // transposes + counter zeroing, one launch
    tr_cvt_all<<<9472, 256, 0, stream>>>(x, Wqkv, Wout, xT, WqkvT, WoutT, cnt);

    // K1: full-G split-K=2 with fused last-block reduction
    gemm_syk256<<<256, 512, 0, stream>>>(xT, Gp, G, cnt);
    // K2 fused: UW2 = [Wq^T G ; Wv^T G]
    gemm_qv256<<<256, 512, 0, stream>>>(WqkvT, G, UW2);
    // K3: per (b,h) small attention
    attn_small<<<dim3(16, 8), 512, 0, stream>>>(UW2, WqkvT, O);
    // K4: out = O @ WoutT^T + bias
    gemm_out<<<dim3(8, 4), 256, 0, stream>>>(O, WoutT, bout, (float*)d_out);
}

// Round 12
// 197.226 us; speedup vs baseline: 1.5524x; 1.5524x over previous
//
#include <hip/hip_runtime.h>
#include <hip/hip_bf16.h>
#include <stdint.h>

typedef _Float16 f16;
typedef _Float16 f16x8 __attribute__((ext_vector_type(8)));
typedef float f32x4 __attribute__((ext_vector_type(4)));

#define AS1 __attribute__((address_space(1)))
#define AS3 __attribute__((address_space(3)))

// ---------------------------------------------------------------------------
// Merged transpose + fp32->fp16 convert for all three inputs, one launch.
// Flat grid decode: [0,8192) x-batches, [8192,9216) Wqkv, [9216,9472) Wout.
// ---------------------------------------------------------------------------
__global__ __launch_bounds__(256) void tr_cvt_all(
    const float* __restrict__ x, const float* __restrict__ Wqkv,
    const float* __restrict__ Wout,
    f16* __restrict__ xT, f16* __restrict__ WqkvT, f16* __restrict__ WoutT)
{
    __shared__ float tile[64][65];
    const int id = blockIdx.x;
    const int t = threadIdx.x;

    const float* src; f16* dst; int R, C, c0, r0;
    if (id < 8192) {
        const int b = id >> 10, rem = id & 1023;
        src = x + (size_t)b * 4096 * 1024;
        dst = xT + (size_t)b * 4096 * 1024;
        R = 4096; C = 1024;
        c0 = (rem & 15) * 64; r0 = (rem >> 4) * 64;
    } else if (id < 9216) {
        const int rem = id - 8192;
        src = Wqkv; dst = WqkvT;
        R = 1024; C = 4096;
        c0 = (rem & 63) * 64; r0 = (rem >> 6) * 64;
    } else {
        const int rem = id - 9216;
        src = Wout; dst = WoutT;
        R = 1024; C = 1024;
        c0 = (rem & 15) * 64; r0 = (rem >> 4) * 64;
    }

    {
        const int cc = (t & 15) * 4;
        const int rr = t >> 4;
#pragma unroll
        for (int p = 0; p < 4; ++p) {
            const int r = rr + p * 16;
            const float4 v = *(const float4*)(src + (size_t)(r0 + r) * C + c0 + cc);
            tile[r][cc + 0] = v.x; tile[r][cc + 1] = v.y;
            tile[r][cc + 2] = v.z; tile[r][cc + 3] = v.w;
        }
    }
    __syncthreads();
    {
        const int rq = (t & 15) * 4;
        const int cp = t >> 4;
#pragma unroll
        for (int p = 0; p < 4; ++p) {
            const int c = cp + p * 16;
            ushort4 o;
            f16 h0 = (f16)tile[rq + 0][c];
            f16 h1 = (f16)tile[rq + 1][c];
            f16 h2 = (f16)tile[rq + 2][c];
            f16 h3 = (f16)tile[rq + 3][c];
            o.x = __builtin_bit_cast(unsigned short, h0);
            o.y = __builtin_bit_cast(unsigned short, h1);
            o.z = __builtin_bit_cast(unsigned short, h2);
            o.w = __builtin_bit_cast(unsigned short, h3);
            *(ushort4*)(dst + (size_t)(c0 + c) * R + r0 + rq) = o;
        }
    }
}

// ---------------------------------------------------------------------------
// r5-exact 256x256-tile, BK=64, 512-thread (8-wave, 2x4) GEMM core.
// Double-buffered LDS, global_load_lds-16B staging one step ahead, counted
// s_waitcnt vmcnt(8) (never 0 mid-loop), raw barriers, chunk-XOR swizzle.
// Measured: 74.8us / MfmaUtil 39.4% / 0 bank conflicts (round 5).
// ---------------------------------------------------------------------------
__device__ __forceinline__ void stage256(
    const f16* __restrict__ src, int ld, char* ldsbase, int tid)
{
    const int lane = tid & 63;
    const int gch = ((lane & 7) ^ (lane >> 3)) * 8;   // inverse-swizzled source
    const int rowl = tid >> 3;
    const int wbase = (tid >> 3) & ~7;                // wave-uniform
#pragma unroll
    for (int p = 0; p < 4; ++p) {
        const f16* s = src + (size_t)(p * 64 + rowl) * ld + gch;
        __builtin_amdgcn_global_load_lds(
            (const AS1 uint32_t*)s,
            (AS3 uint32_t*)(ldsbase + (p * 64 + wbase) * 128), 16, 0, 0);
    }
}

__device__ __forceinline__ void gemm256_core(
    const f16* __restrict__ A, const f16* __restrict__ Bt,
    int lda, int ldb, int nsteps,
    f16* As, f16* Bs, f32x4 (&acc)[8][4], int tid)
{
    const int lane = tid & 63, w = tid >> 6;
    const int wr = w >> 2, wc = w & 3;
    const int cl = lane & 15, kg = lane >> 4, b7 = lane & 7;

    stage256(A, lda, (char*)As, tid);
    stage256(Bt, ldb, (char*)Bs, tid);

#pragma unroll 1
    for (int t = 0; t < nsteps; ++t) {
        const int cur = t & 1;
        if (t + 1 < nsteps) {
            const int k0 = (t + 1) * 64;
            stage256(A + k0, lda, (char*)As + (cur ^ 1) * 32768, tid);
            stage256(Bt + k0, ldb, (char*)Bs + (cur ^ 1) * 32768, tid);
            asm volatile("s_waitcnt vmcnt(8)" ::: "memory");
        } else {
            asm volatile("s_waitcnt vmcnt(0)" ::: "memory");
        }
        __builtin_amdgcn_s_barrier();
        const f16* Ab = As + cur * 16384;
        const f16* Bb = Bs + cur * 16384;
#pragma unroll
        for (int kk = 0; kk < 2; ++kk) {
            const int ch = (kk * 4 + kg) ^ b7;
            f16x8 af[8], bf[4];
#pragma unroll
            for (int i = 0; i < 8; ++i)
                af[i] = *(const f16x8*)&Ab[(wr * 128 + i * 16 + cl) * 64 + ch * 8];
#pragma unroll
            for (int j = 0; j < 4; ++j)
                bf[j] = *(const f16x8*)&Bb[(wc * 64 + j * 16 + cl) * 64 + ch * 8];
#pragma unroll
            for (int i = 0; i < 8; ++i)
#pragma unroll
                for (int j = 0; j < 4; ++j)
                    acc[i][j] = __builtin_amdgcn_mfma_f32_16x16x32_f16(af[i], bf[j], acc[i][j], 0, 0, 0);
        }
        __builtin_amdgcn_s_barrier();
    }
}

// ---------------------------------------------------------------------------
// K1: Gp[s][b] = xT_b[:, s*2048 : +2048] self-product (full G, split-K=2).
// grid: 256 blocks (16 tiles x 8 batch x 2 splits), XCD-chunked swizzle.
// ---------------------------------------------------------------------------
__global__ __launch_bounds__(512, 2) void gemm_syk256(
    const f16* __restrict__ xT, f16* __restrict__ Gp)
{
    __shared__ f16 As[2 * 256 * 64];
    __shared__ f16 Bs[2 * 256 * 64];
    const int orig = blockIdx.x;
    const int l = (orig & 7) * 32 + (orig >> 3);   // 256 = 8*32, bijective
    const int tile = l & 15, b = (l >> 4) & 7, s = l >> 7;
    const int ti = tile >> 2, tj = tile & 3;

    const f16* base = xT + (size_t)b * (1024 * 4096) + (size_t)s * 2048;
    const f16* A  = base + (size_t)ti * 256 * 4096;
    const f16* Bt = base + (size_t)tj * 256 * 4096;

    f32x4 acc[8][4];
#pragma unroll
    for (int i = 0; i < 8; ++i)
#pragma unroll
        for (int j = 0; j < 4; ++j) acc[i][j] = f32x4{0.f, 0.f, 0.f, 0.f};

    gemm256_core(A, Bt, 4096, 4096, 32, As, Bs, acc, threadIdx.x);

    f16* out = Gp + ((size_t)s * 8 + b) * 1048576;
    const int lane = threadIdx.x & 63, w = threadIdx.x >> 6;
    const int wr = w >> 2, wc = w & 3;
    const int cl = lane & 15, rg = lane >> 4;
#pragma unroll
    for (int i = 0; i < 8; ++i)
#pragma unroll
        for (int j = 0; j < 4; ++j)
#pragma unroll
            for (int q = 0; q < 4; ++q) {
                const int row = ti * 256 + wr * 128 + i * 16 + rg * 4 + q;
                const int col = tj * 256 + wc * 64 + j * 16 + cl;
                out[(size_t)row * 1024 + col] = (f16)acc[i][j][q];
            }
}

// ---------------------------------------------------------------------------
// reduce: G = Gp[0] + Gp[1]  (elementwise, f32 accumulate)
// ---------------------------------------------------------------------------
__global__ __launch_bounds__(256) void reduce_sum(
    const f16* __restrict__ Gp, f16* __restrict__ G)
{
    const size_t i = ((size_t)blockIdx.x * 256 + threadIdx.x) * 8;
    const f16x8 a = *(const f16x8*)(Gp + i);
    const f16x8 c = *(const f16x8*)(Gp + 8388608 + i);
    f16x8 o;
#pragma unroll
    for (int j = 0; j < 8; ++j) o[j] = (f16)((float)a[j] + (float)c[j]);
    *(f16x8*)(G + i) = o;
}

// ---------------------------------------------------------------------------
// K2 fused (256^2): UW2[b] = [Wq^T G_b ; Wv^T G_b], K=1024.
// grid: 256 blocks (4 N x 8 M x 8 batch), XCD-chunked swizzle.
// ---------------------------------------------------------------------------
__global__ __launch_bounds__(512, 2) void gemm_qv256(
    const f16* __restrict__ WqkvT, const f16* __restrict__ G,
    f16* __restrict__ UW2)
{
    __shared__ f16 As[2 * 256 * 64];
    __shared__ f16 Bs[2 * 256 * 64];
    const int orig = blockIdx.x;
    const int l = (orig & 7) * 32 + (orig >> 3);
    const int bx = l & 3, by = (l >> 2) & 7, b = l >> 5;
    const int arow = (by < 4) ? by * 256 : 2048 + (by - 4) * 256;  // skip Wk

    const f16* A  = WqkvT + (size_t)arow * 1024;
    const f16* Bt = G + (size_t)b * 1048576 + (size_t)bx * 256 * 1024;

    f32x4 acc[8][4];
#pragma unroll
    for (int i = 0; i < 8; ++i)
#pragma unroll
        for (int j = 0; j < 4; ++j) acc[i][j] = f32x4{0.f, 0.f, 0.f, 0.f};

    gemm256_core(A, Bt, 1024, 1024, 16, As, Bs, acc, threadIdx.x);

    f16* C = UW2 + (size_t)b * 2097152;
    const int lane = threadIdx.x & 63, w = threadIdx.x >> 6;
    const int wr = w >> 2, wc = w & 3;
    const int cl = lane & 15, rg = lane >> 4;
#pragma unroll
    for (int i = 0; i < 8; ++i)
#pragma unroll
        for (int j = 0; j < 4; ++j) {
            const int cc = bx * 256 + wc * 64 + j * 16 + cl;
#pragma unroll
            for (int q = 0; q < 4; ++q) {
                const int rr = by * 256 + wr * 128 + i * 16 + rg * 4 + q;
                C[(size_t)rr * 1024 + cc] = (f16)acc[i][j][q];
            }
        }
}

// ---------------------------------------------------------------------------
// Legacy 128x128 body (used by gemm_out only)
// ---------------------------------------------------------------------------
__device__ __forceinline__ void gemm_body(
    const f16* __restrict__ A, const f16* __restrict__ Bt,
    int lda, int ldb, int K, f16* As, f16* Bs,
    f32x4 (&acc)[4][4], int tid)
{
    const int lane = tid & 63, w = tid >> 6;
    const int wr = w >> 1, wc = w & 1;
    const int lrow = lane >> 3;
    const int lcol = (lane & 7) * 8;
    for (int k0 = 0; k0 < K; k0 += 64) {
#pragma unroll
        for (int p = 0; p < 4; ++p) {
            const f16* sa = A + (size_t)(p * 32 + w * 8 + lrow) * lda + k0 + lcol;
            __builtin_amdgcn_global_load_lds(
                (const AS1 uint32_t*)sa,
                (AS3 uint32_t*)((char*)As + p * 4096 + w * 1024), 16, 0, 0);
            const f16* sb = Bt + (size_t)(p * 32 + w * 8 + lrow) * ldb + k0 + lcol;
            __builtin_amdgcn_global_load_lds(
                (const AS1 uint32_t*)sb,
                (AS3 uint32_t*)((char*)Bs + p * 4096 + w * 1024), 16, 0, 0);
        }
        __syncthreads();
#pragma unroll
        for (int kk = 0; kk < 2; ++kk) {
            f16x8 af[4], bfr[4];
#pragma unroll
            for (int i = 0; i < 4; ++i)
                af[i] = *(const f16x8*)&As[(wr * 64 + i * 16 + (lane & 15)) * 64 + kk * 32 + (lane >> 4) * 8];
#pragma unroll
            for (int j = 0; j < 4; ++j)
                bfr[j] = *(const f16x8*)&Bs[(wc * 64 + j * 16 + (lane & 15)) * 64 + kk * 32 + (lane >> 4) * 8];
#pragma unroll
            for (int i = 0; i < 4; ++i)
#pragma unroll
                for (int j = 0; j < 4; ++j)
                    acc[i][j] = __builtin_amdgcn_mfma_f32_16x16x32_f16(af[i], bfr[j], acc[i][j], 0, 0, 0);
        }
        __syncthreads();
    }
}

// ---------------------------------------------------------------------------
// K4: d_out = O @ WoutT^T + bias.  grid (8,4), block 256. K=1024.
// ---------------------------------------------------------------------------
__global__ __launch_bounds__(256) void gemm_out(
    const f16* __restrict__ A, const f16* __restrict__ Bt,
    const float* __restrict__ bias, float* __restrict__ Cout)
{
    __shared__ f16 As[128 * 64];
    __shared__ f16 Bs[128 * 64];
    const int tn0 = blockIdx.x * 128;
    const int tm0 = blockIdx.y * 128;
    f32x4 acc[4][4];
#pragma unroll
    for (int i = 0; i < 4; ++i)
#pragma unroll
        for (int j = 0; j < 4; ++j) acc[i][j] = f32x4{0.f, 0.f, 0.f, 0.f};

    gemm_body(A + (size_t)tm0 * 1024, Bt + (size_t)tn0 * 1024,
              1024, 1024, 1024, As, Bs, acc, threadIdx.x);

    const int lane = threadIdx.x & 63, w = threadIdx.x >> 6;
    const int wr = w >> 1, wc = w & 1;
    const int cl = lane & 15, rg = lane >> 4;
#pragma unroll
    for (int i = 0; i < 4; ++i)
#pragma unroll
        for (int j = 0; j < 4; ++j) {
            const int cc = tn0 + wc * 64 + j * 16 + cl;
            const float bv = bias[cc];
#pragma unroll
            for (int q = 0; q < 4; ++q) {
                const int rr = tm0 + wr * 64 + i * 16 + rg * 4 + q;
                Cout[(size_t)rr * 1024 + cc] = acc[i][j][q] + bv;
            }
        }
}

// ---------------------------------------------------------------------------
// Per (b,h): dots = U_h * Wk_h^T, vv = W2_h * Wv2_h^T  (64x64, K=1024),
// softmax(dots*0.125), out = attn @ vv -> O (f16)
// grid: (16 heads, 8 batches), block 512 (8 waves)
// ---------------------------------------------------------------------------
__global__ __launch_bounds__(512) void attn_small(
    const f16* __restrict__ UW2, const f16* __restrict__ WqkvT,
    f16* __restrict__ O)
{
    __shared__ float dots[64][66];
    __shared__ float vv[64][66];
    const int h = blockIdx.x, b = blockIdx.y;
    const int tid = threadIdx.x, lane = tid & 63, w = tid >> 6;
    const int isVV = w >> 2;
    const int kq = w & 3;

    const f16* Arows = UW2 + (size_t)b * (2048 * 1024)
                           + (size_t)isVV * (1024 * 1024) + (size_t)h * 64 * 1024;
    const f16* Brows = WqkvT + (size_t)(isVV ? 3072 : 1024) * 1024 + (size_t)h * 64 * 1024;

    f32x4 acc[4][4];
#pragma unroll
    for (int i = 0; i < 4; ++i)
#pragma unroll
        for (int j = 0; j < 4; ++j) acc[i][j] = f32x4{0.f, 0.f, 0.f, 0.f};

    const int cl = lane & 15, kg = lane >> 4;
    for (int ks = 0; ks < 8; ++ks) {
        const int k0 = kq * 256 + ks * 32 + kg * 8;
        f16x8 af[4], bfr[4];
#pragma unroll
        for (int i = 0; i < 4; ++i)
            af[i] = *(const f16x8*)(Arows + (size_t)(i * 16 + cl) * 1024 + k0);
#pragma unroll
        for (int j = 0; j < 4; ++j)
            bfr[j] = *(const f16x8*)(Brows + (size_t)(j * 16 + cl) * 1024 + k0);
#pragma unroll
        for (int i = 0; i < 4; ++i)
#pragma unroll
            for (int j = 0; j < 4; ++j)
                acc[i][j] = __builtin_amdgcn_mfma_f32_16x16x32_f16(af[i], bfr[j], acc[i][j], 0, 0, 0);
    }

    float (*dst)[66] = isVV ? vv : dots;
#pragma unroll
    for (int r = 0; r < 4; ++r) {
        if (kq == r) {
            if (r == 0) {
#pragma unroll
                for (int i = 0; i < 4; ++i)
#pragma unroll
                    for (int j = 0; j < 4; ++j)
#pragma unroll
                        for (int q = 0; q < 4; ++q)
                            dst[i * 16 + kg * 4 + q][j * 16 + cl] = acc[i][j][q];
            } else {
#pragma unroll
                for (int i = 0; i < 4; ++i)
#pragma unroll
                    for (int j = 0; j < 4; ++j)
#pragma unroll
                        for (int q = 0; q < 4; ++q)
                            dst[i * 16 + kg * 4 + q][j * 16 + cl] += acc[i][j][q];
            }
        }
        __syncthreads();
    }

    if (tid < 64) {
        const int r = tid;
        float mx = -1e30f;
        for (int e = 0; e < 64; ++e) {
            const float v = dots[r][e] * 0.125f;
            dots[r][e] = v;
            mx = fmaxf(mx, v);
        }
        float s = 0.f;
        for (int e = 0; e < 64; ++e) {
            const float v = __expf(dots[r][e] - mx);
            dots[r][e] = v;
            s += v;
        }
        const float inv = 1.f / s;
        for (int e = 0; e < 64; ++e) dots[r][e] *= inv;
    }
    __syncthreads();

    {
        const int r = tid >> 3, f0 = (tid & 7) * 8;
        float o[8];
#pragma unroll
        for (int i = 0; i < 8; ++i) o[i] = 0.f;
        for (int e = 0; e < 64; ++e) {
            const float a = dots[r][e];
#pragma unroll
            for (int i = 0; i < 8; ++i) o[i] += a * vv[e][f0 + i];
        }
        f16* Od = O + (size_t)b * 64 * 1024 + (size_t)r * 1024 + h * 64 + f0;
#pragma unroll
        for (int i = 0; i < 8; ++i) Od[i] = (f16)o[i];
    }
}

// ---------------------------------------------------------------------------
extern "C" void kernel_launch(void* const* d_in, const int* in_sizes, int n_in,
                              void* d_out, int out_size, void* d_ws, size_t ws_size,
                              hipStream_t stream)
{
    const float* x    = (const float*)d_in[0];  // [8][4096][1024]
    const float* Wqkv = (const float*)d_in[1];  // [1024][4096]
    const float* Wout = (const float*)d_in[2];  // [1024][1024]
    const float* bout = (const float*)d_in[3];  // [1024]

    char* ws = (char*)d_ws;
    f16* xT    = (f16*)(ws + 0);           // [8][1024][4096]   67108864 B
    f16* WqkvT = (f16*)(ws + 67108864);    // [4096][1024]       8388608 B
    f16* WoutT = (f16*)(ws + 75497472);    // [1024][1024]       2097152 B
    f16* G     = (f16*)(ws + 77594624);    // [8][1024][1024]   16777216 B
    f16* Gp    = (f16*)(ws + 94371840);    // [2][8][1024][1024] 33554432 B
    f16* UW2   = (f16*)(ws + 94371840);    // union w/ Gp (qv runs after reduce)
    f16* O     = (f16*)(ws + 127926272);   // [8][64][1024]      1048576 B

    // all transposes, one launch
    tr_cvt_all<<<9472, 256, 0, stream>>>(x, Wqkv, Wout, xT, WqkvT, WoutT);

    // K1: full-G split-K=2, 256^2 tiles, counted-vmcnt pipelined (r5 core)
    gemm_syk256<<<256, 512, 0, stream>>>(xT, Gp);
    // G = Gp0 + Gp1
    reduce_sum<<<4096, 256, 0, stream>>>(Gp, G);
    // K2 fused: UW2 = [Wq^T G ; Wv^T G]
    gemm_qv256<<<256, 512, 0, stream>>>(WqkvT, G, UW2);
    // K3: per (b,h) small attention
    attn_small<<<dim3(16, 8), 512, 0, stream>>>(UW2, WqkvT, O);
    // K4: out = O @ WoutT^T + bias
    gemm_out<<<dim3(8, 4), 256, 0, stream>>>(O, WoutT, bout, (float*)d_out);
}

// Round 13
// 180.069 us; speedup vs baseline: 1.7003x; 1.0953x over previous
//
#include <hip/hip_runtime.h>
#include <hip/hip_bf16.h>
#include <stdint.h>

typedef _Float16 f16;
typedef _Float16 f16x8 __attribute__((ext_vector_type(8)));
typedef float f32x4 __attribute__((ext_vector_type(4)));

#define AS1 __attribute__((address_space(1)))
#define AS3 __attribute__((address_space(3)))

// ---------------------------------------------------------------------------
// Merged transpose + fp32->fp16 convert for all three inputs, one launch.
// Flat grid decode: [0,8192) x-batches, [8192,9216) Wqkv, [9216,9472) Wout.
// ---------------------------------------------------------------------------
__global__ __launch_bounds__(256) void tr_cvt_all(
    const float* __restrict__ x, const float* __restrict__ Wqkv,
    const float* __restrict__ Wout,
    f16* __restrict__ xT, f16* __restrict__ WqkvT, f16* __restrict__ WoutT)
{
    __shared__ float tile[64][65];
    const int id = blockIdx.x;
    const int t = threadIdx.x;

    const float* src; f16* dst; int R, C, c0, r0;
    if (id < 8192) {
        const int b = id >> 10, rem = id & 1023;
        src = x + (size_t)b * 4096 * 1024;
        dst = xT + (size_t)b * 4096 * 1024;
        R = 4096; C = 1024;
        c0 = (rem & 15) * 64; r0 = (rem >> 4) * 64;
    } else if (id < 9216) {
        const int rem = id - 8192;
        src = Wqkv; dst = WqkvT;
        R = 1024; C = 4096;
        c0 = (rem & 63) * 64; r0 = (rem >> 6) * 64;
    } else {
        const int rem = id - 9216;
        src = Wout; dst = WoutT;
        R = 1024; C = 1024;
        c0 = (rem & 15) * 64; r0 = (rem >> 4) * 64;
    }

    {
        const int cc = (t & 15) * 4;
        const int rr = t >> 4;
#pragma unroll
        for (int p = 0; p < 4; ++p) {
            const int r = rr + p * 16;
            const float4 v = *(const float4*)(src + (size_t)(r0 + r) * C + c0 + cc);
            tile[r][cc + 0] = v.x; tile[r][cc + 1] = v.y;
            tile[r][cc + 2] = v.z; tile[r][cc + 3] = v.w;
        }
    }
    __syncthreads();
    {
        const int rq = (t & 15) * 4;
        const int cp = t >> 4;
#pragma unroll
        for (int p = 0; p < 4; ++p) {
            const int c = cp + p * 16;
            ushort4 o;
            f16 h0 = (f16)tile[rq + 0][c];
            f16 h1 = (f16)tile[rq + 1][c];
            f16 h2 = (f16)tile[rq + 2][c];
            f16 h3 = (f16)tile[rq + 3][c];
            o.x = __builtin_bit_cast(unsigned short, h0);
            o.y = __builtin_bit_cast(unsigned short, h1);
            o.z = __builtin_bit_cast(unsigned short, h2);
            o.w = __builtin_bit_cast(unsigned short, h3);
            *(ushort4*)(dst + (size_t)(c0 + c) * R + r0 + rq) = o;
        }
    }
}

// ---------------------------------------------------------------------------
// r5-exact 256x256-tile, BK=64, 512-thread (8-wave, 2x4) GEMM core.
// Double-buffered LDS, global_load_lds-16B staging one step ahead, counted
// s_waitcnt vmcnt(8) (never 0 mid-loop), raw barriers, chunk-XOR swizzle.
// Measured: 74.8us / MfmaUtil 39.4% / 0 bank conflicts (round 5).
// ---------------------------------------------------------------------------
__device__ __forceinline__ void stage256(
    const f16* __restrict__ src, int ld, char* ldsbase, int tid)
{
    const int lane = tid & 63;
    const int gch = ((lane & 7) ^ (lane >> 3)) * 8;   // inverse-swizzled source
    const int rowl = tid >> 3;
    const int wbase = (tid >> 3) & ~7;                // wave-uniform
#pragma unroll
    for (int p = 0; p < 4; ++p) {
        const f16* s = src + (size_t)(p * 64 + rowl) * ld + gch;
        __builtin_amdgcn_global_load_lds(
            (const AS1 uint32_t*)s,
            (AS3 uint32_t*)(ldsbase + (p * 64 + wbase) * 128), 16, 0, 0);
    }
}

__device__ __forceinline__ void gemm256_core(
    const f16* __restrict__ A, const f16* __restrict__ Bt,
    int lda, int ldb, int nsteps,
    f16* As, f16* Bs, f32x4 (&acc)[8][4], int tid)
{
    const int lane = tid & 63, w = tid >> 6;
    const int wr = w >> 2, wc = w & 3;
    const int cl = lane & 15, kg = lane >> 4, b7 = lane & 7;

    stage256(A, lda, (char*)As, tid);
    stage256(Bt, ldb, (char*)Bs, tid);

#pragma unroll 1
    for (int t = 0; t < nsteps; ++t) {
        const int cur = t & 1;
        if (t + 1 < nsteps) {
            const int k0 = (t + 1) * 64;
            stage256(A + k0, lda, (char*)As + (cur ^ 1) * 32768, tid);
            stage256(Bt + k0, ldb, (char*)Bs + (cur ^ 1) * 32768, tid);
            asm volatile("s_waitcnt vmcnt(8)" ::: "memory");
        } else {
            asm volatile("s_waitcnt vmcnt(0)" ::: "memory");
        }
        __builtin_amdgcn_s_barrier();
        const f16* Ab = As + cur * 16384;
        const f16* Bb = Bs + cur * 16384;
#pragma unroll
        for (int kk = 0; kk < 2; ++kk) {
            const int ch = (kk * 4 + kg) ^ b7;
            f16x8 af[8], bf[4];
#pragma unroll
            for (int i = 0; i < 8; ++i)
                af[i] = *(const f16x8*)&Ab[(wr * 128 + i * 16 + cl) * 64 + ch * 8];
#pragma unroll
            for (int j = 0; j < 4; ++j)
                bf[j] = *(const f16x8*)&Bb[(wc * 64 + j * 16 + cl) * 64 + ch * 8];
#pragma unroll
            for (int i = 0; i < 8; ++i)
#pragma unroll
                for (int j = 0; j < 4; ++j)
                    acc[i][j] = __builtin_amdgcn_mfma_f32_16x16x32_f16(af[i], bf[j], acc[i][j], 0, 0, 0);
        }
        __builtin_amdgcn_s_barrier();
    }
}

// ---------------------------------------------------------------------------
// K1: upper-triangle 256^2 tiles of G_b = xT_b xT_b^T, split-K=3 (22/21/21
// steps). grid: 240 blocks = 10 tiles x 8 batch x 3 splits, XCD swizzle.
// Gp layout: [s][b][u][256][256] f16 compact.
// ---------------------------------------------------------------------------
__global__ __launch_bounds__(512, 2) void gemm_syk256(
    const f16* __restrict__ xT, f16* __restrict__ Gp)
{
    __shared__ f16 As[2 * 256 * 64];
    __shared__ f16 Bs[2 * 256 * 64];
    const int orig = blockIdx.x;
    const int l = (orig & 7) * 30 + (orig >> 3);   // 240 = 8*30, bijective
    const int u = l % 10;
    const int b = (l / 10) & 7;
    const int s = l / 80;
    int ti = 0, rem = u;
    while (rem >= 4 - ti) { rem -= 4 - ti; ++ti; }
    const int tj = ti + rem;
    const int koff = (s == 0) ? 0 : (1408 + (s - 1) * 1344);
    const int nst  = (s == 0) ? 22 : 21;

    const f16* base = xT + (size_t)b * (1024 * 4096) + koff;
    const f16* A  = base + (size_t)ti * 256 * 4096;
    const f16* Bt = base + (size_t)tj * 256 * 4096;

    f32x4 acc[8][4];
#pragma unroll
    for (int i = 0; i < 8; ++i)
#pragma unroll
        for (int j = 0; j < 4; ++j) acc[i][j] = f32x4{0.f, 0.f, 0.f, 0.f};

    gemm256_core(A, Bt, 4096, 4096, nst, As, Bs, acc, threadIdx.x);

    f16* out = Gp + ((size_t)s * 80 + b * 10 + u) * 65536;
    const int lane = threadIdx.x & 63, w = threadIdx.x >> 6;
    const int wr = w >> 2, wc = w & 3;
    const int cl = lane & 15, rg = lane >> 4;
#pragma unroll
    for (int i = 0; i < 8; ++i)
#pragma unroll
        for (int j = 0; j < 4; ++j)
#pragma unroll
            for (int q = 0; q < 4; ++q) {
                const int row = wr * 128 + i * 16 + rg * 4 + q;
                const int col = wc * 64 + j * 16 + cl;
                out[row * 256 + col] = (f16)acc[i][j][q];
            }
}

// ---------------------------------------------------------------------------
// reduce_mirror: G tile = sum of 3 split partials; off-diagonal tiles also
// write the transposed mirror tile. grid (4 quarters, 10 tiles, 8 batch),
// block 256. LDS 128x129 f32 transpose (conflict-free). r3-proven pattern.
// ---------------------------------------------------------------------------
__global__ __launch_bounds__(256) void reduce_mirror(
    const f16* __restrict__ Gp, f16* __restrict__ G)
{
    __shared__ float tile[128][129];
    const int q = blockIdx.x, u = blockIdx.y, b = blockIdx.z;
    int ti = 0, rem = u;
    while (rem >= 4 - ti) { rem -= 4 - ti; ++ti; }
    const int tj = ti + rem;
    const int qr = q >> 1, qc = q & 1;
    const size_t tb = ((size_t)b * 10 + u) * 65536;
    const size_t sstride = (size_t)80 * 65536;
    f16* Gb = G + (size_t)b * 1048576;
    const int t = threadIdx.x;

#pragma unroll
    for (int i = 0; i < 8; ++i) {
        const int e = (i * 256 + t) * 8;
        const int r = e >> 7, c = e & 127;
        const size_t src = tb + (size_t)(qr * 128 + r) * 256 + qc * 128 + c;
        float sum[8];
#pragma unroll
        for (int j = 0; j < 8; ++j) sum[j] = 0.f;
#pragma unroll
        for (int sp = 0; sp < 3; ++sp) {
            const f16x8 v = *(const f16x8*)(Gp + sp * sstride + src);
#pragma unroll
            for (int j = 0; j < 8; ++j) sum[j] += (float)v[j];
        }
        f16x8 o;
#pragma unroll
        for (int j = 0; j < 8; ++j) {
            o[j] = (f16)sum[j];
            tile[r][c + j] = sum[j];
        }
        *(f16x8*)(Gb + (size_t)(ti * 256 + qr * 128 + r) * 1024
                     + tj * 256 + qc * 128 + c) = o;
    }
    if (ti != tj) {
        __syncthreads();
#pragma unroll
        for (int i = 0; i < 8; ++i) {
            const int e = (i * 256 + t) * 8;
            const int R = e >> 7, C = e & 127;
            f16x8 o;
#pragma unroll
            for (int j = 0; j < 8; ++j) o[j] = (f16)tile[C + j][R];
            *(f16x8*)(Gb + (size_t)(tj * 256 + qc * 128 + R) * 1024
                         + ti * 256 + qr * 128 + C) = o;
        }
    }
}

// ---------------------------------------------------------------------------
// K2 fused (256^2): UW2[b] = [Wq^T G_b ; Wv^T G_b], K=1024.
// grid: 256 blocks (4 N x 8 M x 8 batch), XCD-chunked swizzle.
// ---------------------------------------------------------------------------
__global__ __launch_bounds__(512, 2) void gemm_qv256(
    const f16* __restrict__ WqkvT, const f16* __restrict__ G,
    f16* __restrict__ UW2)
{
    __shared__ f16 As[2 * 256 * 64];
    __shared__ f16 Bs[2 * 256 * 64];
    const int orig = blockIdx.x;
    const int l = (orig & 7) * 32 + (orig >> 3);
    const int bx = l & 3, by = (l >> 2) & 7, b = l >> 5;
    const int arow = (by < 4) ? by * 256 : 2048 + (by - 4) * 256;  // skip Wk

    const f16* A  = WqkvT + (size_t)arow * 1024;
    const f16* Bt = G + (size_t)b * 1048576 + (size_t)bx * 256 * 1024;

    f32x4 acc[8][4];
#pragma unroll
    for (int i = 0; i < 8; ++i)
#pragma unroll
        for (int j = 0; j < 4; ++j) acc[i][j] = f32x4{0.f, 0.f, 0.f, 0.f};

    gemm256_core(A, Bt, 1024, 1024, 16, As, Bs, acc, threadIdx.x);

    f16* C = UW2 + (size_t)b * 2097152;
    const int lane = threadIdx.x & 63, w = threadIdx.x >> 6;
    const int wr = w >> 2, wc = w & 3;
    const int cl = lane & 15, rg = lane >> 4;
#pragma unroll
    for (int i = 0; i < 8; ++i)
#pragma unroll
        for (int j = 0; j < 4; ++j) {
            const int cc = bx * 256 + wc * 64 + j * 16 + cl;
#pragma unroll
            for (int q = 0; q < 4; ++q) {
                const int rr = by * 256 + wr * 128 + i * 16 + rg * 4 + q;
                C[(size_t)rr * 1024 + cc] = (f16)acc[i][j][q];
            }
        }
}

// ---------------------------------------------------------------------------
// Legacy 128x128 body (used by gemm_out only)
// ---------------------------------------------------------------------------
__device__ __forceinline__ void gemm_body(
    const f16* __restrict__ A, const f16* __restrict__ Bt,
    int lda, int ldb, int K, f16* As, f16* Bs,
    f32x4 (&acc)[4][4], int tid)
{
    const int lane = tid & 63, w = tid >> 6;
    const int wr = w >> 1, wc = w & 1;
    const int lrow = lane >> 3;
    const int lcol = (lane & 7) * 8;
    for (int k0 = 0; k0 < K; k0 += 64) {
#pragma unroll
        for (int p = 0; p < 4; ++p) {
            const f16* sa = A + (size_t)(p * 32 + w * 8 + lrow) * lda + k0 + lcol;
            __builtin_amdgcn_global_load_lds(
                (const AS1 uint32_t*)sa,
                (AS3 uint32_t*)((char*)As + p * 4096 + w * 1024), 16, 0, 0);
            const f16* sb = Bt + (size_t)(p * 32 + w * 8 + lrow) * ldb + k0 + lcol;
            __builtin_amdgcn_global_load_lds(
                (const AS1 uint32_t*)sb,
                (AS3 uint32_t*)((char*)Bs + p * 4096 + w * 1024), 16, 0, 0);
        }
        __syncthreads();
#pragma unroll
        for (int kk = 0; kk < 2; ++kk) {
            f16x8 af[4], bfr[4];
#pragma unroll
            for (int i = 0; i < 4; ++i)
                af[i] = *(const f16x8*)&As[(wr * 64 + i * 16 + (lane & 15)) * 64 + kk * 32 + (lane >> 4) * 8];
#pragma unroll
            for (int j = 0; j < 4; ++j)
                bfr[j] = *(const f16x8*)&Bs[(wc * 64 + j * 16 + (lane & 15)) * 64 + kk * 32 + (lane >> 4) * 8];
#pragma unroll
            for (int i = 0; i < 4; ++i)
#pragma unroll
                for (int j = 0; j < 4; ++j)
                    acc[i][j] = __builtin_amdgcn_mfma_f32_16x16x32_f16(af[i], bfr[j], acc[i][j], 0, 0, 0);
        }
        __syncthreads();
    }
}

// ---------------------------------------------------------------------------
// K4: d_out = O @ WoutT^T + bias.  grid (8,4), block 256. K=1024.
// ---------------------------------------------------------------------------
__global__ __launch_bounds__(256) void gemm_out(
    const f16* __restrict__ A, const f16* __restrict__ Bt,
    const float* __restrict__ bias, float* __restrict__ Cout)
{
    __shared__ f16 As[128 * 64];
    __shared__ f16 Bs[128 * 64];
    const int tn0 = blockIdx.x * 128;
    const int tm0 = blockIdx.y * 128;
    f32x4 acc[4][4];
#pragma unroll
    for (int i = 0; i < 4; ++i)
#pragma unroll
        for (int j = 0; j < 4; ++j) acc[i][j] = f32x4{0.f, 0.f, 0.f, 0.f};

    gemm_body(A + (size_t)tm0 * 1024, Bt + (size_t)tn0 * 1024,
              1024, 1024, 1024, As, Bs, acc, threadIdx.x);

    const int lane = threadIdx.x & 63, w = threadIdx.x >> 6;
    const int wr = w >> 1, wc = w & 1;
    const int cl = lane & 15, rg = lane >> 4;
#pragma unroll
    for (int i = 0; i < 4; ++i)
#pragma unroll
        for (int j = 0; j < 4; ++j) {
            const int cc = tn0 + wc * 64 + j * 16 + cl;
            const float bv = bias[cc];
#pragma unroll
            for (int q = 0; q < 4; ++q) {
                const int rr = tm0 + wr * 64 + i * 16 + rg * 4 + q;
                Cout[(size_t)rr * 1024 + cc] = acc[i][j][q] + bv;
            }
        }
}

// ---------------------------------------------------------------------------
// Per (b,h): dots = U_h * Wk_h^T, vv = W2_h * Wv2_h^T  (64x64, K=1024),
// softmax(dots*0.125), out = attn @ vv -> O (f16)
// grid: (16 heads, 8 batches), block 512 (8 waves)
// ---------------------------------------------------------------------------
__global__ __launch_bounds__(512) void attn_small(
    const f16* __restrict__ UW2, const f16* __restrict__ WqkvT,
    f16* __restrict__ O)
{
    __shared__ float dots[64][66];
    __shared__ float vv[64][66];
    const int h = blockIdx.x, b = blockIdx.y;
    const int tid = threadIdx.x, lane = tid & 63, w = tid >> 6;
    const int isVV = w >> 2;
    const int kq = w & 3;

    const f16* Arows = UW2 + (size_t)b * (2048 * 1024)
                           + (size_t)isVV * (1024 * 1024) + (size_t)h * 64 * 1024;
    const f16* Brows = WqkvT + (size_t)(isVV ? 3072 : 1024) * 1024 + (size_t)h * 64 * 1024;

    f32x4 acc[4][4];
#pragma unroll
    for (int i = 0; i < 4; ++i)
#pragma unroll
        for (int j = 0; j < 4; ++j) acc[i][j] = f32x4{0.f, 0.f, 0.f, 0.f};

    const int cl = lane & 15, kg = lane >> 4;
    for (int ks = 0; ks < 8; ++ks) {
        const int k0 = kq * 256 + ks * 32 + kg * 8;
        f16x8 af[4], bfr[4];
#pragma unroll
        for (int i = 0; i < 4; ++i)
            af[i] = *(const f16x8*)(Arows + (size_t)(i * 16 + cl) * 1024 + k0);
#pragma unroll
        for (int j = 0; j < 4; ++j)
            bfr[j] = *(const f16x8*)(Brows + (size_t)(j * 16 + cl) * 1024 + k0);
#pragma unroll
        for (int i = 0; i < 4; ++i)
#pragma unroll
            for (int j = 0; j < 4; ++j)
                acc[i][j] = __builtin_amdgcn_mfma_f32_16x16x32_f16(af[i], bfr[j], acc[i][j], 0, 0, 0);
    }

    float (*dst)[66] = isVV ? vv : dots;
#pragma unroll
    for (int r = 0; r < 4; ++r) {
        if (kq == r) {
            if (r == 0) {
#pragma unroll
                for (int i = 0; i < 4; ++i)
#pragma unroll
                    for (int j = 0; j < 4; ++j)
#pragma unroll
                        for (int q = 0; q < 4; ++q)
                            dst[i * 16 + kg * 4 + q][j * 16 + cl] = acc[i][j][q];
            } else {
#pragma unroll
                for (int i = 0; i < 4; ++i)
#pragma unroll
                    for (int j = 0; j < 4; ++j)
#pragma unroll
                        for (int q = 0; q < 4; ++q)
                            dst[i * 16 + kg * 4 + q][j * 16 + cl] += acc[i][j][q];
            }
        }
        __syncthreads();
    }

    if (tid < 64) {
        const int r = tid;
        float mx = -1e30f;
        for (int e = 0; e < 64; ++e) {
            const float v = dots[r][e] * 0.125f;
            dots[r][e] = v;
            mx = fmaxf(mx, v);
        }
        float s = 0.f;
        for (int e = 0; e < 64; ++e) {
            const float v = __expf(dots[r][e] - mx);
            dots[r][e] = v;
            s += v;
        }
        const float inv = 1.f / s;
        for (int e = 0; e < 64; ++e) dots[r][e] *= inv;
    }
    __syncthreads();

    {
        const int r = tid >> 3, f0 = (tid & 7) * 8;
        float o[8];
#pragma unroll
        for (int i = 0; i < 8; ++i) o[i] = 0.f;
        for (int e = 0; e < 64; ++e) {
            const float a = dots[r][e];
#pragma unroll
            for (int i = 0; i < 8; ++i) o[i] += a * vv[e][f0 + i];
        }
        f16* Od = O + (size_t)b * 64 * 1024 + (size_t)r * 1024 + h * 64 + f0;
#pragma unroll
        for (int i = 0; i < 8; ++i) Od[i] = (f16)o[i];
    }
}

// ---------------------------------------------------------------------------
extern "C" void kernel_launch(void* const* d_in, const int* in_sizes, int n_in,
                              void* d_out, int out_size, void* d_ws, size_t ws_size,
                              hipStream_t stream)
{
    const float* x    = (const float*)d_in[0];  // [8][4096][1024]
    const float* Wqkv = (const float*)d_in[1];  // [1024][4096]
    const float* Wout = (const float*)d_in[2];  // [1024][1024]
    const float* bout = (const float*)d_in[3];  // [1024]

    char* ws = (char*)d_ws;
    f16* xT    = (f16*)(ws + 0);           // [8][1024][4096]   67108864 B
    f16* WqkvT = (f16*)(ws + 67108864);    // [4096][1024]       8388608 B
    f16* WoutT = (f16*)(ws + 75497472);    // [1024][1024]       2097152 B
    f16* G     = (f16*)(ws + 77594624);    // [8][1024][1024]   16777216 B
    f16* Gp    = (f16*)(ws + 94371840);    // [3][8][10][65536] 31457280 B
    f16* UW2   = (f16*)(ws + 94371840);    // union w/ Gp (qv runs after reduce)
    f16* O     = (f16*)(ws + 127926272);   // [8][64][1024]      1048576 B

    // all transposes, one launch
    tr_cvt_all<<<9472, 256, 0, stream>>>(x, Wqkv, Wout, xT, WqkvT, WoutT);

    // K1: upper-triangle tiles, split-K=3, 256^2, counted-vmcnt (r5 core)
    gemm_syk256<<<240, 512, 0, stream>>>(xT, Gp);
    // G = sum of 3 partials + mirror off-diagonal tiles
    reduce_mirror<<<dim3(4, 10, 8), 256, 0, stream>>>(Gp, G);
    // K2 fused: UW2 = [Wq^T G ; Wv^T G]
    gemm_qv256<<<256, 512, 0, stream>>>(WqkvT, G, UW2);
    // K3: per (b,h) small attention
    attn_small<<<dim3(16, 8), 512, 0, stream>>>(UW2, WqkvT, O);
    // K4: out = O @ WoutT^T + bias
    gemm_out<<<dim3(8, 4), 256, 0, stream>>>(O, WoutT, bout, (float*)d_out);
}

// Round 14
// 172.720 us; speedup vs baseline: 1.7726x; 1.0426x over previous
//
#include <hip/hip_runtime.h>
#include <hip/hip_bf16.h>
#include <stdint.h>

typedef _Float16 f16;
typedef _Float16 f16x8 __attribute__((ext_vector_type(8)));
typedef float f32x4 __attribute__((ext_vector_type(4)));

#define AS1 __attribute__((address_space(1)))
#define AS3 __attribute__((address_space(3)))

// ---------------------------------------------------------------------------
// Merged transpose + fp32->fp16 convert for all three inputs + bias-init of
// d_out, one launch. Flat grid decode: [0,8192) x-batches, [8192,9216) Wqkv,
// [9216,9472) Wout, [9472,9984) d_out = bias rows (for gemm_out atomics).
// ---------------------------------------------------------------------------
__global__ __launch_bounds__(256) void tr_cvt_all(
    const float* __restrict__ x, const float* __restrict__ Wqkv,
    const float* __restrict__ Wout, const float* __restrict__ bias,
    f16* __restrict__ xT, f16* __restrict__ WqkvT, f16* __restrict__ WoutT,
    float* __restrict__ outInit)
{
    __shared__ float tile[64][65];
    const int id = blockIdx.x;
    const int t = threadIdx.x;

    if (id >= 9472) {   // bias init: d_out[512][1024] = bias broadcast
        const int blk = id - 9472;
        const int idx = blk * 1024 + t * 4;
        const float4 bv = *(const float4*)(bias + (t * 4));
        *(float4*)(outInit + idx) = bv;
        return;
    }

    const float* src; f16* dst; int R, C, c0, r0;
    if (id < 8192) {
        const int b = id >> 10, rem = id & 1023;
        src = x + (size_t)b * 4096 * 1024;
        dst = xT + (size_t)b * 4096 * 1024;
        R = 4096; C = 1024;
        c0 = (rem & 15) * 64; r0 = (rem >> 4) * 64;
    } else if (id < 9216) {
        const int rem = id - 8192;
        src = Wqkv; dst = WqkvT;
        R = 1024; C = 4096;
        c0 = (rem & 63) * 64; r0 = (rem >> 6) * 64;
    } else {
        const int rem = id - 9216;
        src = Wout; dst = WoutT;
        R = 1024; C = 1024;
        c0 = (rem & 15) * 64; r0 = (rem >> 4) * 64;
    }

    {
        const int cc = (t & 15) * 4;
        const int rr = t >> 4;
#pragma unroll
        for (int p = 0; p < 4; ++p) {
            const int r = rr + p * 16;
            const float4 v = *(const float4*)(src + (size_t)(r0 + r) * C + c0 + cc);
            tile[r][cc + 0] = v.x; tile[r][cc + 1] = v.y;
            tile[r][cc + 2] = v.z; tile[r][cc + 3] = v.w;
        }
    }
    __syncthreads();
    {
        const int rq = (t & 15) * 4;
        const int cp = t >> 4;
#pragma unroll
        for (int p = 0; p < 4; ++p) {
            const int c = cp + p * 16;
            ushort4 o;
            f16 h0 = (f16)tile[rq + 0][c];
            f16 h1 = (f16)tile[rq + 1][c];
            f16 h2 = (f16)tile[rq + 2][c];
            f16 h3 = (f16)tile[rq + 3][c];
            o.x = __builtin_bit_cast(unsigned short, h0);
            o.y = __builtin_bit_cast(unsigned short, h1);
            o.z = __builtin_bit_cast(unsigned short, h2);
            o.w = __builtin_bit_cast(unsigned short, h3);
            *(ushort4*)(dst + (size_t)(c0 + c) * R + r0 + rq) = o;
        }
    }
}

// ---------------------------------------------------------------------------
// r5-exact 256x256-tile, BK=64, 512-thread (8-wave, 2x4) GEMM core.
// Double-buffered LDS, global_load_lds-16B staging one step ahead, counted
// s_waitcnt vmcnt(8) (never 0 mid-loop), raw barriers, chunk-XOR swizzle.
// Measured: 74.8us / MfmaUtil 39.4% / 0 bank conflicts (round 5).
// ---------------------------------------------------------------------------
__device__ __forceinline__ void stage256(
    const f16* __restrict__ src, int ld, char* ldsbase, int tid)
{
    const int lane = tid & 63;
    const int gch = ((lane & 7) ^ (lane >> 3)) * 8;   // inverse-swizzled source
    const int rowl = tid >> 3;
    const int wbase = (tid >> 3) & ~7;                // wave-uniform
#pragma unroll
    for (int p = 0; p < 4; ++p) {
        const f16* s = src + (size_t)(p * 64 + rowl) * ld + gch;
        __builtin_amdgcn_global_load_lds(
            (const AS1 uint32_t*)s,
            (AS3 uint32_t*)(ldsbase + (p * 64 + wbase) * 128), 16, 0, 0);
    }
}

__device__ __forceinline__ void gemm256_core(
    const f16* __restrict__ A, const f16* __restrict__ Bt,
    int lda, int ldb, int nsteps,
    f16* As, f16* Bs, f32x4 (&acc)[8][4], int tid)
{
    const int lane = tid & 63, w = tid >> 6;
    const int wr = w >> 2, wc = w & 3;
    const int cl = lane & 15, kg = lane >> 4, b7 = lane & 7;

    stage256(A, lda, (char*)As, tid);
    stage256(Bt, ldb, (char*)Bs, tid);

#pragma unroll 1
    for (int t = 0; t < nsteps; ++t) {
        const int cur = t & 1;
        if (t + 1 < nsteps) {
            const int k0 = (t + 1) * 64;
            stage256(A + k0, lda, (char*)As + (cur ^ 1) * 32768, tid);
            stage256(Bt + k0, ldb, (char*)Bs + (cur ^ 1) * 32768, tid);
            asm volatile("s_waitcnt vmcnt(8)" ::: "memory");
        } else {
            asm volatile("s_waitcnt vmcnt(0)" ::: "memory");
        }
        __builtin_amdgcn_s_barrier();
        const f16* Ab = As + cur * 16384;
        const f16* Bb = Bs + cur * 16384;
#pragma unroll
        for (int kk = 0; kk < 2; ++kk) {
            const int ch = (kk * 4 + kg) ^ b7;
            f16x8 af[8], bf[4];
#pragma unroll
            for (int i = 0; i < 8; ++i)
                af[i] = *(const f16x8*)&Ab[(wr * 128 + i * 16 + cl) * 64 + ch * 8];
#pragma unroll
            for (int j = 0; j < 4; ++j)
                bf[j] = *(const f16x8*)&Bb[(wc * 64 + j * 16 + cl) * 64 + ch * 8];
#pragma unroll
            for (int i = 0; i < 8; ++i)
#pragma unroll
                for (int j = 0; j < 4; ++j)
                    acc[i][j] = __builtin_amdgcn_mfma_f32_16x16x32_f16(af[i], bf[j], acc[i][j], 0, 0, 0);
        }
        __builtin_amdgcn_s_barrier();
    }
}

// ---------------------------------------------------------------------------
// K1: upper-triangle 256^2 tiles of G_b = xT_b xT_b^T, split-K=3 (22/21/21
// steps). grid: 240 blocks = 10 tiles x 8 batch x 3 splits, XCD swizzle.
// Gp layout: [s][b][u][256][256] f16 compact.
// ---------------------------------------------------------------------------
__global__ __launch_bounds__(512, 2) void gemm_syk256(
    const f16* __restrict__ xT, f16* __restrict__ Gp)
{
    __shared__ f16 As[2 * 256 * 64];
    __shared__ f16 Bs[2 * 256 * 64];
    const int orig = blockIdx.x;
    const int l = (orig & 7) * 30 + (orig >> 3);   // 240 = 8*30, bijective
    const int u = l % 10;
    const int b = (l / 10) & 7;
    const int s = l / 80;
    int ti = 0, rem = u;
    while (rem >= 4 - ti) { rem -= 4 - ti; ++ti; }
    const int tj = ti + rem;
    const int koff = (s == 0) ? 0 : (1408 + (s - 1) * 1344);
    const int nst  = (s == 0) ? 22 : 21;

    const f16* base = xT + (size_t)b * (1024 * 4096) + koff;
    const f16* A  = base + (size_t)ti * 256 * 4096;
    const f16* Bt = base + (size_t)tj * 256 * 4096;

    f32x4 acc[8][4];
#pragma unroll
    for (int i = 0; i < 8; ++i)
#pragma unroll
        for (int j = 0; j < 4; ++j) acc[i][j] = f32x4{0.f, 0.f, 0.f, 0.f};

    gemm256_core(A, Bt, 4096, 4096, nst, As, Bs, acc, threadIdx.x);

    f16* out = Gp + ((size_t)s * 80 + b * 10 + u) * 65536;
    const int lane = threadIdx.x & 63, w = threadIdx.x >> 6;
    const int wr = w >> 2, wc = w & 3;
    const int cl = lane & 15, rg = lane >> 4;
#pragma unroll
    for (int i = 0; i < 8; ++i)
#pragma unroll
        for (int j = 0; j < 4; ++j)
#pragma unroll
            for (int q = 0; q < 4; ++q) {
                const int row = wr * 128 + i * 16 + rg * 4 + q;
                const int col = wc * 64 + j * 16 + cl;
                out[row * 256 + col] = (f16)acc[i][j][q];
            }
}

// ---------------------------------------------------------------------------
// reduce_mirror: G tile = sum of 3 split partials; off-diagonal tiles also
// write the transposed mirror tile. grid (4 quarters, 10 tiles, 8 batch),
// block 256. LDS 128x129 f32 transpose (conflict-free). r3-proven pattern.
// ---------------------------------------------------------------------------
__global__ __launch_bounds__(256) void reduce_mirror(
    const f16* __restrict__ Gp, f16* __restrict__ G)
{
    __shared__ float tile[128][129];
    const int q = blockIdx.x, u = blockIdx.y, b = blockIdx.z;
    int ti = 0, rem = u;
    while (rem >= 4 - ti) { rem -= 4 - ti; ++ti; }
    const int tj = ti + rem;
    const int qr = q >> 1, qc = q & 1;
    const size_t tb = ((size_t)b * 10 + u) * 65536;
    const size_t sstride = (size_t)80 * 65536;
    f16* Gb = G + (size_t)b * 1048576;
    const int t = threadIdx.x;

#pragma unroll
    for (int i = 0; i < 8; ++i) {
        const int e = (i * 256 + t) * 8;
        const int r = e >> 7, c = e & 127;
        const size_t src = tb + (size_t)(qr * 128 + r) * 256 + qc * 128 + c;
        float sum[8];
#pragma unroll
        for (int j = 0; j < 8; ++j) sum[j] = 0.f;
#pragma unroll
        for (int sp = 0; sp < 3; ++sp) {
            const f16x8 v = *(const f16x8*)(Gp + sp * sstride + src);
#pragma unroll
            for (int j = 0; j < 8; ++j) sum[j] += (float)v[j];
        }
        f16x8 o;
#pragma unroll
        for (int j = 0; j < 8; ++j) {
            o[j] = (f16)sum[j];
            tile[r][c + j] = sum[j];
        }
        *(f16x8*)(Gb + (size_t)(ti * 256 + qr * 128 + r) * 1024
                     + tj * 256 + qc * 128 + c) = o;
    }
    if (ti != tj) {
        __syncthreads();
#pragma unroll
        for (int i = 0; i < 8; ++i) {
            const int e = (i * 256 + t) * 8;
            const int R = e >> 7, C = e & 127;
            f16x8 o;
#pragma unroll
            for (int j = 0; j < 8; ++j) o[j] = (f16)tile[C + j][R];
            *(f16x8*)(Gb + (size_t)(tj * 256 + qc * 128 + R) * 1024
                         + ti * 256 + qr * 128 + C) = o;
        }
    }
}

// ---------------------------------------------------------------------------
// K2 fused (256^2): UW2[b] = [Wq^T G_b ; Wv^T G_b], K=1024.
// grid: 256 blocks (4 N x 8 M x 8 batch), XCD-chunked swizzle.
// ---------------------------------------------------------------------------
__global__ __launch_bounds__(512, 2) void gemm_qv256(
    const f16* __restrict__ WqkvT, const f16* __restrict__ G,
    f16* __restrict__ UW2)
{
    __shared__ f16 As[2 * 256 * 64];
    __shared__ f16 Bs[2 * 256 * 64];
    const int orig = blockIdx.x;
    const int l = (orig & 7) * 32 + (orig >> 3);
    const int bx = l & 3, by = (l >> 2) & 7, b = l >> 5;
    const int arow = (by < 4) ? by * 256 : 2048 + (by - 4) * 256;  // skip Wk

    const f16* A  = WqkvT + (size_t)arow * 1024;
    const f16* Bt = G + (size_t)b * 1048576 + (size_t)bx * 256 * 1024;

    f32x4 acc[8][4];
#pragma unroll
    for (int i = 0; i < 8; ++i)
#pragma unroll
        for (int j = 0; j < 4; ++j) acc[i][j] = f32x4{0.f, 0.f, 0.f, 0.f};

    gemm256_core(A, Bt, 1024, 1024, 16, As, Bs, acc, threadIdx.x);

    f16* C = UW2 + (size_t)b * 2097152;
    const int lane = threadIdx.x & 63, w = threadIdx.x >> 6;
    const int wr = w >> 2, wc = w & 3;
    const int cl = lane & 15, rg = lane >> 4;
#pragma unroll
    for (int i = 0; i < 8; ++i)
#pragma unroll
        for (int j = 0; j < 4; ++j) {
            const int cc = bx * 256 + wc * 64 + j * 16 + cl;
#pragma unroll
            for (int q = 0; q < 4; ++q) {
                const int rr = by * 256 + wr * 128 + i * 16 + rg * 4 + q;
                C[(size_t)rr * 1024 + cc] = (f16)acc[i][j][q];
            }
        }
}

// ---------------------------------------------------------------------------
// Legacy 128x128 body (used by gemm_out only)
// ---------------------------------------------------------------------------
__device__ __forceinline__ void gemm_body(
    const f16* __restrict__ A, const f16* __restrict__ Bt,
    int lda, int ldb, int K, f16* As, f16* Bs,
    f32x4 (&acc)[4][4], int tid)
{
    const int lane = tid & 63, w = tid >> 6;
    const int wr = w >> 1, wc = w & 1;
    const int lrow = lane >> 3;
    const int lcol = (lane & 7) * 8;
    for (int k0 = 0; k0 < K; k0 += 64) {
#pragma unroll
        for (int p = 0; p < 4; ++p) {
            const f16* sa = A + (size_t)(p * 32 + w * 8 + lrow) * lda + k0 + lcol;
            __builtin_amdgcn_global_load_lds(
                (const AS1 uint32_t*)sa,
                (AS3 uint32_t*)((char*)As + p * 4096 + w * 1024), 16, 0, 0);
            const f16* sb = Bt + (size_t)(p * 32 + w * 8 + lrow) * ldb + k0 + lcol;
            __builtin_amdgcn_global_load_lds(
                (const AS1 uint32_t*)sb,
                (AS3 uint32_t*)((char*)Bs + p * 4096 + w * 1024), 16, 0, 0);
        }
        __syncthreads();
#pragma unroll
        for (int kk = 0; kk < 2; ++kk) {
            f16x8 af[4], bfr[4];
#pragma unroll
            for (int i = 0; i < 4; ++i)
                af[i] = *(const f16x8*)&As[(wr * 64 + i * 16 + (lane & 15)) * 64 + kk * 32 + (lane >> 4) * 8];
#pragma unroll
            for (int j = 0; j < 4; ++j)
                bfr[j] = *(const f16x8*)&Bs[(wc * 64 + j * 16 + (lane & 15)) * 64 + kk * 32 + (lane >> 4) * 8];
#pragma unroll
            for (int i = 0; i < 4; ++i)
#pragma unroll
                for (int j = 0; j < 4; ++j)
                    acc[i][j] = __builtin_amdgcn_mfma_f32_16x16x32_f16(af[i], bfr[j], acc[i][j], 0, 0, 0);
        }
        __syncthreads();
    }
}

// ---------------------------------------------------------------------------
// K4: d_out += O @ WoutT^T (d_out pre-initialized to bias by tr_cvt_all).
// split-K=2 via f32 atomics. grid (8,4,2), block 256.
// ---------------------------------------------------------------------------
__global__ __launch_bounds__(256) void gemm_out(
    const f16* __restrict__ A, const f16* __restrict__ Bt,
    float* __restrict__ Cout)
{
    __shared__ f16 As[128 * 64];
    __shared__ f16 Bs[128 * 64];
    const int tn0 = blockIdx.x * 128;
    const int tm0 = blockIdx.y * 128;
    const int s = blockIdx.z;
    f32x4 acc[4][4];
#pragma unroll
    for (int i = 0; i < 4; ++i)
#pragma unroll
        for (int j = 0; j < 4; ++j) acc[i][j] = f32x4{0.f, 0.f, 0.f, 0.f};

    gemm_body(A + (size_t)tm0 * 1024 + s * 512,
              Bt + (size_t)tn0 * 1024 + s * 512, 1024, 1024, 512,
              As, Bs, acc, threadIdx.x);

    const int lane = threadIdx.x & 63, w = threadIdx.x >> 6;
    const int wr = w >> 1, wc = w & 1;
    const int cl = lane & 15, rg = lane >> 4;
#pragma unroll
    for (int i = 0; i < 4; ++i)
#pragma unroll
        for (int j = 0; j < 4; ++j) {
            const int cc = tn0 + wc * 64 + j * 16 + cl;
#pragma unroll
            for (int q = 0; q < 4; ++q) {
                const int rr = tm0 + wr * 64 + i * 16 + rg * 4 + q;
                atomicAdd(&Cout[(size_t)rr * 1024 + cc], acc[i][j][q]);
            }
        }
}

// ---------------------------------------------------------------------------
// Per (b,h): dots = U_h * Wk_h^T, vv = W2_h * Wv2_h^T  (64x64, K=1024),
// softmax(dots*0.125), out = attn @ vv -> O (f16)
// grid: (16 heads, 8 batches), block 512 (8 waves)
// ---------------------------------------------------------------------------
__global__ __launch_bounds__(512) void attn_small(
    const f16* __restrict__ UW2, const f16* __restrict__ WqkvT,
    f16* __restrict__ O)
{
    __shared__ float dots[64][66];
    __shared__ float vv[64][66];
    const int h = blockIdx.x, b = blockIdx.y;
    const int tid = threadIdx.x, lane = tid & 63, w = tid >> 6;
    const int isVV = w >> 2;
    const int kq = w & 3;

    const f16* Arows = UW2 + (size_t)b * (2048 * 1024)
                           + (size_t)isVV * (1024 * 1024) + (size_t)h * 64 * 1024;
    const f16* Brows = WqkvT + (size_t)(isVV ? 3072 : 1024) * 1024 + (size_t)h * 64 * 1024;

    f32x4 acc[4][4];
#pragma unroll
    for (int i = 0; i < 4; ++i)
#pragma unroll
        for (int j = 0; j < 4; ++j) acc[i][j] = f32x4{0.f, 0.f, 0.f, 0.f};

    const int cl = lane & 15, kg = lane >> 4;
    for (int ks = 0; ks < 8; ++ks) {
        const int k0 = kq * 256 + ks * 32 + kg * 8;
        f16x8 af[4], bfr[4];
#pragma unroll
        for (int i = 0; i < 4; ++i)
            af[i] = *(const f16x8*)(Arows + (size_t)(i * 16 + cl) * 1024 + k0);
#pragma unroll
        for (int j = 0; j < 4; ++j)
            bfr[j] = *(const f16x8*)(Brows + (size_t)(j * 16 + cl) * 1024 + k0);
#pragma unroll
        for (int i = 0; i < 4; ++i)
#pragma unroll
            for (int j = 0; j < 4; ++j)
                acc[i][j] = __builtin_amdgcn_mfma_f32_16x16x32_f16(af[i], bfr[j], acc[i][j], 0, 0, 0);
    }

    float (*dst)[66] = isVV ? vv : dots;
#pragma unroll
    for (int r = 0; r < 4; ++r) {
        if (kq == r) {
            if (r == 0) {
#pragma unroll
                for (int i = 0; i < 4; ++i)
#pragma unroll
                    for (int j = 0; j < 4; ++j)
#pragma unroll
                        for (int q = 0; q < 4; ++q)
                            dst[i * 16 + kg * 4 + q][j * 16 + cl] = acc[i][j][q];
            } else {
#pragma unroll
                for (int i = 0; i < 4; ++i)
#pragma unroll
                    for (int j = 0; j < 4; ++j)
#pragma unroll
                        for (int q = 0; q < 4; ++q)
                            dst[i * 16 + kg * 4 + q][j * 16 + cl] += acc[i][j][q];
            }
        }
        __syncthreads();
    }

    if (tid < 64) {
        const int r = tid;
        float mx = -1e30f;
        for (int e = 0; e < 64; ++e) {
            const float v = dots[r][e] * 0.125f;
            dots[r][e] = v;
            mx = fmaxf(mx, v);
        }
        float s = 0.f;
        for (int e = 0; e < 64; ++e) {
            const float v = __expf(dots[r][e] - mx);
            dots[r][e] = v;
            s += v;
        }
        const float inv = 1.f / s;
        for (int e = 0; e < 64; ++e) dots[r][e] *= inv;
    }
    __syncthreads();

    {
        const int r = tid >> 3, f0 = (tid & 7) * 8;
        float o[8];
#pragma unroll
        for (int i = 0; i < 8; ++i) o[i] = 0.f;
        for (int e = 0; e < 64; ++e) {
            const float a = dots[r][e];
#pragma unroll
            for (int i = 0; i < 8; ++i) o[i] += a * vv[e][f0 + i];
        }
        f16* Od = O + (size_t)b * 64 * 1024 + (size_t)r * 1024 + h * 64 + f0;
#pragma unroll
        for (int i = 0; i < 8; ++i) Od[i] = (f16)o[i];
    }
}

// ---------------------------------------------------------------------------
extern "C" void kernel_launch(void* const* d_in, const int* in_sizes, int n_in,
                              void* d_out, int out_size, void* d_ws, size_t ws_size,
                              hipStream_t stream)
{
    const float* x    = (const float*)d_in[0];  // [8][4096][1024]
    const float* Wqkv = (const float*)d_in[1];  // [1024][4096]
    const float* Wout = (const float*)d_in[2];  // [1024][1024]
    const float* bout = (const float*)d_in[3];  // [1024]

    char* ws = (char*)d_ws;
    f16* xT    = (f16*)(ws + 0);           // [8][1024][4096]   67108864 B
    f16* WqkvT = (f16*)(ws + 67108864);    // [4096][1024]       8388608 B
    f16* WoutT = (f16*)(ws + 75497472);    // [1024][1024]       2097152 B
    f16* G     = (f16*)(ws + 77594624);    // [8][1024][1024]   16777216 B
    f16* Gp    = (f16*)(ws + 94371840);    // [3][8][10][65536] 31457280 B
    f16* UW2   = (f16*)(ws + 94371840);    // union w/ Gp (qv runs after reduce)
    f16* O     = (f16*)(ws + 127926272);   // [8][64][1024]      1048576 B

    // all transposes + d_out bias init, one launch
    tr_cvt_all<<<9984, 256, 0, stream>>>(x, Wqkv, Wout, bout,
                                         xT, WqkvT, WoutT, (float*)d_out);

    // K1: upper-triangle tiles, split-K=3, 256^2, counted-vmcnt (r5 core)
    gemm_syk256<<<240, 512, 0, stream>>>(xT, Gp);
    // G = sum of 3 partials + mirror off-diagonal tiles
    reduce_mirror<<<dim3(4, 10, 8), 256, 0, stream>>>(Gp, G);
    // K2 fused: UW2 = [Wq^T G ; Wv^T G]
    gemm_qv256<<<256, 512, 0, stream>>>(WqkvT, G, UW2);
    // K3: per (b,h) small attention
    attn_small<<<dim3(16, 8), 512, 0, stream>>>(UW2, WqkvT, O);
    // K4: d_out += O @ WoutT^T (split-K=2, f32 atomics; bias pre-initialized)
    gemm_out<<<dim3(8, 4, 2), 256, 0, stream>>>(O, WoutT, (float*)d_out);
}